// Round 7
// baseline (344.232 us; speedup 1.0000x reference)
//
#include <hip/hip_runtime.h>

#define NB 1000000
#define NA 40
#define THREADS 256
#define WPB (THREADS / 64)                      // waves per block
#define NBLOCKS 2048
#define CHUNK 32                                // samples per wave-chunk
#define NCHUNKS (NB / CHUNK)                    // 31250, exact
#define NEG_LN2_OVER_A (-0.017328679513998632f) // -ln(2)/40

// Round-7: get under the 64-VGPR occupancy cliff (m69: waves/SIMD halve at
// vgpr=64). Rounds 4/6 (VGPR 84) sat at 26% occ / 2.7 TB/s; round 5 proved
// a VGPR<=64 kernel runs 58% occ / 4.5 TB/s even WITH spill traffic.
// Changes vs round 4: chunk 64->32 samples (xv: 40->20 VGPRs); label batch
// replaced by load+__ballot (the ballot IS the transpose, result in SGPRs,
// zero VGPR in-flight cost); weight table replaced by per-ELEM shfl
// (-20 VGPRs). launch_bounds(256,8) caps at 64; natural pressure ~50 so no
// round-5-style spill expected (WRITE_SIZE is the tripwire).
__global__ __launch_bounds__(THREADS, 8) void focal_loss_kernel(
    const float* __restrict__ inputs,    // [NB, NA] f32
    const int*   __restrict__ targets,   // [NA, NB] i32 in {0,1}
    const float* __restrict__ attr_w,    // [NA] f32
    float* __restrict__ out)             // [1] f32 (pre-zeroed)
{
    __shared__ float s_red[WPB];
    const int lane = threadIdx.x & 63;
    const int wid  = blockIdx.x * WPB + (threadIdx.x >> 6);
    const int W    = NBLOCKS * WPB;

    // lane a holds attr_w[a], pre-scaled by -ln2/40 (fetched per-ELEM via shfl)
    float awl = 0.0f;
    if (lane < NA) awl = attr_w[lane] * NEG_LN2_OVER_A;

    // lane-constant slice tables: slice j handles float4 f = lane + 64j
    int rj[5], sj[5];
    #pragma unroll
    for (int j = 0; j < 5; ++j) {
        const int f = lane + 64 * j;
        const int s = f / 10;          // sample within chunk, 0..31
        rj[j] = 4 * (f - 10 * s);      // attr base (0,4,...,36)
        sj[j] = s;                     // bit position in W_a
    }

    float acc = 0.0f;

    for (int ch = wid; ch < NCHUNKS; ch += W) {
        const int s0 = ch * CHUNK;

        // ---- inputs: 5 coalesced float4 loads (chunk = 5 KB contiguous) ----
        const float4* in4 = (const float4*)inputs + (size_t)s0 * 10;
        float4 xv[5];
        #pragma unroll
        for (int j = 0; j < 5; ++j) xv[j] = in4[lane + 64 * j];

        // ---- labels: 20 coalesced dword loads; ballot = in-register
        //      transpose -> lane a ends up holding W_a (bits of 32 samples) --
        unsigned Wbits = 0u;
        #pragma unroll
        for (int k = 0; k < 20; ++k) {
            const int a  = 2 * k + (lane >> 5);                 // attrs 2k,2k+1
            const int tv = targets[(size_t)a * NB + (s0 + (lane & 31))];
            const unsigned long long m = __ballot(tv != 0);     // bit l = lane l's label
            Wbits = (lane == 2 * k)     ? (unsigned)m         : Wbits;  // lo = attr 2k
            Wbits = (lane == 2 * k + 1) ? (unsigned)(m >> 32) : Wbits;  // hi = attr 2k+1
        }

        // ---- compute: per ELEM fetch W_a and weight from lane a via shfl ---
        #pragma unroll
        for (int j = 0; j < 5; ++j) {
            const int r  = rj[j];
            const int si = sj[j];
            const float xs[4] = {xv[j].x, xv[j].y, xv[j].z, xv[j].w};
            #pragma unroll
            for (int c = 0; c < 4; ++c) {
                const int a = r + c;
                const unsigned Wa = (unsigned)__shfl((int)Wbits, a, 64);
                const float wgt   = __shfl(awl, a, 64);
                const float x_  = xs[c];
                const float om_ = 1.0f - x_;
                const float w_  = wgt * (om_ * om_);
                const float p_  = fmaxf(x_,  1e-12f);
                const float q_  = fmaxf(om_, 1e-12f);
                acc = fmaf(w_, __log2f(((Wa >> si) & 1u) ? p_ : q_), acc);
            }
        }
    }

    // ---- reduce: 64-lane shuffle -> cross-wave LDS -> one atomic/block ----
    float v = acc;   // weights already carry -ln2/40
    #pragma unroll
    for (int off = 32; off > 0; off >>= 1)
        v += __shfl_xor(v, off, 64);
    const int t = threadIdx.x;
    if ((t & 63) == 0) s_red[t >> 6] = v;
    __syncthreads();
    if (t == 0) {
        float r2 = 0.0f;
        #pragma unroll
        for (int w2 = 0; w2 < WPB; ++w2) r2 += s_red[w2];
        atomicAdd(out, r2);
    }
}

extern "C" void kernel_launch(void* const* d_in, const int* in_sizes, int n_in,
                              void* d_out, int out_size, void* d_ws, size_t ws_size,
                              hipStream_t stream) {
    const float* inputs  = (const float*)d_in[0];
    const int*   targets = (const int*)d_in[1];
    const float* attr_w  = (const float*)d_in[2];
    float* out = (float*)d_out;
    hipMemsetAsync(out, 0, sizeof(float), stream);
    focal_loss_kernel<<<dim3(NBLOCKS), dim3(THREADS), 0, stream>>>(inputs, targets, attr_w, out);
}